// Round 1
// baseline (359.038 us; speedup 1.0000x reference)
//
#include <hip/hip_runtime.h>
#include <hip/hip_bf16.h>
#include <cstdint>

// VanillaLSTMCell: B=8192, I=H=1024.
// z = [x|h] @ [Wx;Wh]^T + b  (M=8192, N=4096, K=2048), LSTM pointwise fused.
//
// ROUND 5: barrier-free GEMM. A and W are packed in MFMA-FRAGMENT-MAJOR order
//   [tile][kt][wave_half][frag][lane][8bf16]
// so each wave loads its fragments with coalesced global_load_dwordx4 DIRECTLY
// into VGPRs -- no LDS, no __syncthreads in the K-loop, fine-grained vmcnt
// waits only (the AITER-style structure the m97 2-barrier loop can't express).
// Gate mapping folded into W pack: ni == gate for 16 j's per wave tile ->
// register-resident LSTM epilogue (round 4).

typedef __bf16 bf16;
typedef __attribute__((ext_vector_type(8))) bf16 bf16x8;
typedef __attribute__((ext_vector_type(4))) float f32x4;

#define CN_OFF 8388608  // 8192*1024, c_next offset in d_out

// ---- pack kernel ----
// blocks [0,8192):    A2[mb(64)][kt(64)][wm(2)][mi(4)][lane(64)][8]
//                     m = mb*128 + wm*64 + mi*16 + (lane&15), k = kt*32 + (lane>>4)*8
// blocks [8192,12288): B2[nb(32)][kt(64)][wn(2)][gate(4)][lane(64)][8]
//                     j = (nb*2+wn)*16 + (lane&15), k = kt*32 + (lane>>4)*8
// Bias: Bcomb[(nb*2+wn)*64 + gate*16 + jl] = bx[j]+bh[j]
__global__ __launch_bounds__(256) void pack_all(
    const float* __restrict__ x, const float* __restrict__ h,
    const float* __restrict__ wxi, const float* __restrict__ whi,
    const float* __restrict__ wxf, const float* __restrict__ whf,
    const float* __restrict__ wxo, const float* __restrict__ who,
    const float* __restrict__ wxg, const float* __restrict__ whg,
    const float* __restrict__ bxi, const float* __restrict__ bhi,
    const float* __restrict__ bxf, const float* __restrict__ bhf,
    const float* __restrict__ bxo, const float* __restrict__ bho,
    const float* __restrict__ bxg, const float* __restrict__ bhg,
    bf16* __restrict__ A2, bf16* __restrict__ B2, float* __restrict__ Bcomb) {
  int b = blockIdx.x;
  if (b < 8192) {
    int chunk = b * 256 + threadIdx.x;        // 2,097,152 chunks of 8
    int lane = chunk & 63;
    int mi   = (chunk >> 6) & 3;
    int wm   = (chunk >> 8) & 1;
    int kt   = (chunk >> 9) & 63;
    int mb   = chunk >> 15;
    int m = mb * 128 + wm * 64 + mi * 16 + (lane & 15);
    int k = kt * 32 + (lane >> 4) * 8;
    const float* src = (k < 1024) ? (x + (size_t)m * 1024 + k)
                                  : (h + (size_t)m * 1024 + (k - 1024));
    f32x4 v0 = *(const f32x4*)src;
    f32x4 v1 = *(const f32x4*)(src + 4);
    bf16x8 o;
    o[0]=(bf16)v0[0]; o[1]=(bf16)v0[1]; o[2]=(bf16)v0[2]; o[3]=(bf16)v0[3];
    o[4]=(bf16)v1[0]; o[5]=(bf16)v1[1]; o[6]=(bf16)v1[2]; o[7]=(bf16)v1[3];
    *(bf16x8*)(A2 + (size_t)chunk * 8) = o;
  } else {
    int chunk = (b - 8192) * 256 + threadIdx.x;  // 1,048,576 chunks of 8
    int lane = chunk & 63;
    int gate = (chunk >> 6) & 3;
    int wn   = (chunk >> 8) & 1;
    int kt   = (chunk >> 9) & 63;
    int nb   = chunk >> 15;
    int jl = lane & 15;
    int j  = (nb * 2 + wn) * 16 + jl;
    int k  = kt * 32 + (lane >> 4) * 8;
    const float* wx = (gate == 0) ? wxi : (gate == 1) ? wxf : (gate == 2) ? wxo : wxg;
    const float* wh = (gate == 0) ? whi : (gate == 1) ? whf : (gate == 2) ? who : whg;
    const float* src = (k < 1024) ? (wx + (size_t)j * 1024 + k)
                                  : (wh + (size_t)j * 1024 + (k - 1024));
    f32x4 v0 = *(const f32x4*)src;
    f32x4 v1 = *(const f32x4*)(src + 4);
    bf16x8 o;
    o[0]=(bf16)v0[0]; o[1]=(bf16)v0[1]; o[2]=(bf16)v0[2]; o[3]=(bf16)v0[3];
    o[4]=(bf16)v1[0]; o[5]=(bf16)v1[1]; o[6]=(bf16)v1[2]; o[7]=(bf16)v1[3];
    *(bf16x8*)(B2 + (size_t)chunk * 8) = o;
    if (kt == 0 && (lane >> 4) == 0) {
      const float* bx = (gate == 0) ? bxi : (gate == 1) ? bxf : (gate == 2) ? bxo : bxg;
      const float* bh = (gate == 0) ? bhi : (gate == 1) ? bhf : (gate == 2) ? bho : bhg;
      Bcomb[(nb * 2 + wn) * 64 + gate * 16 + jl] = bx[j] + bh[j];
    }
  }
}

__device__ __forceinline__ float sigf(float v) { return 1.f / (1.f + __expf(-v)); }
__device__ __forceinline__ float tanhfast(float v) {
  v = fminf(15.f, fmaxf(-15.f, v));
  float e = __expf(2.f * v);
  return (e - 1.f) / (e + 1.f);
}

// ---- barrier-free fragment-direct GEMM + register-resident LSTM epilogue ----
__global__ __launch_bounds__(256) void gemm_lstm(const bf16* __restrict__ A2,
                                                 const bf16* __restrict__ B2,
                                                 const float* __restrict__ Bcomb,
                                                 const float* __restrict__ c,
                                                 float* __restrict__ out) {
  const int t    = threadIdx.x;
  const int wave = t >> 6;
  const int lane = t & 63;
  const int nb = blockIdx.x;     // 32 N-tiles
  const int mb = blockIdx.y;     // 64 M-tiles
  const int wm = wave >> 1;      // wave's 64-row half
  const int wn = wave & 1;       // wave's 64-col half
  const int lrow = lane & 15;
  const int lkg  = lane >> 4;

  // fragment-major bases: offset(kt,frag) = kt*4096 + frag*512 (elements)
  const bf16* pa = A2 + (size_t)mb * 262144 + wm * 2048 + lane * 8;
  const bf16* pb = B2 + (size_t)nb * 262144 + wn * 2048 + lane * 8;

  f32x4 acc[4][4] = {};   // acc[mi][gate]
  bf16x8 a0[4], b0[4], a1[4], b1[4];

#pragma unroll
  for (int i = 0; i < 4; ++i) {
    a0[i] = *(const bf16x8*)(pa + i * 512);
    b0[i] = *(const bf16x8*)(pb + i * 512);
  }
#pragma unroll
  for (int i = 0; i < 4; ++i) {
    a1[i] = *(const bf16x8*)(pa + 4096 + i * 512);
    b1[i] = *(const bf16x8*)(pb + 4096 + i * 512);
  }

  for (int kt = 0; kt < 64; kt += 2) {
#pragma unroll
    for (int mi = 0; mi < 4; ++mi)
#pragma unroll
      for (int ni = 0; ni < 4; ++ni)
        acc[mi][ni] = __builtin_amdgcn_mfma_f32_16x16x32_bf16(a0[mi], b0[ni], acc[mi][ni], 0, 0, 0);
    if (kt + 2 < 64) {
      const bf16* qa = pa + (size_t)(kt + 2) * 4096;
      const bf16* qb = pb + (size_t)(kt + 2) * 4096;
#pragma unroll
      for (int i = 0; i < 4; ++i) {
        a0[i] = *(const bf16x8*)(qa + i * 512);
        b0[i] = *(const bf16x8*)(qb + i * 512);
      }
    }
#pragma unroll
    for (int mi = 0; mi < 4; ++mi)
#pragma unroll
      for (int ni = 0; ni < 4; ++ni)
        acc[mi][ni] = __builtin_amdgcn_mfma_f32_16x16x32_bf16(a1[mi], b1[ni], acc[mi][ni], 0, 0, 0);
    if (kt + 3 < 64) {
      const bf16* qa = pa + (size_t)(kt + 3) * 4096;
      const bf16* qb = pb + (size_t)(kt + 3) * 4096;
#pragma unroll
      for (int i = 0; i < 4; ++i) {
        a1[i] = *(const bf16x8*)(qa + i * 512);
        b1[i] = *(const bf16x8*)(qb + i * 512);
      }
    }
  }

  // ---- register-resident LSTM epilogue (round-4 mapping) ----
  // Lane (lrow,lkg): j = (nb*2+wn)*16 + lrow; rows = mb*128 + wm*64 + mi*16 + lkg*4 + r
  const int jg = (nb * 2 + wn) * 16 + lrow;
  const int bbase = (nb * 2 + wn) * 64 + lrow;
  const float bi  = Bcomb[bbase +  0];
  const float bf_ = Bcomb[bbase + 16];
  const float bo  = Bcomb[bbase + 32];
  const float bg  = Bcomb[bbase + 48];

#pragma unroll
  for (int mi = 0; mi < 4; ++mi) {
    const int row0 = mb * 128 + wm * 64 + mi * 16 + lkg * 4;
    float cv[4];
#pragma unroll
    for (int r = 0; r < 4; ++r)
      cv[r] = c[(size_t)(row0 + r) * 1024 + jg];
#pragma unroll
    for (int r = 0; r < 4; ++r) {
      float zi = acc[mi][0][r] + bi;
      float zf = acc[mi][1][r] + bf_;
      float zo = acc[mi][2][r] + bo;
      float zg = acc[mi][3][r] + bg;
      float it = sigf(zi), ft = sigf(zf), ot = sigf(zo), gt = tanhfast(zg);
      float cn = ft * cv[r] + it * gt;
      size_t off = (size_t)(row0 + r) * 1024 + jg;
      out[off] = ot * tanhfast(cn);        // h_next
      out[CN_OFF + off] = cn;              // c_next
    }
  }
}

extern "C" void kernel_launch(void* const* d_in, const int* in_sizes, int n_in,
                              void* d_out, int out_size, void* d_ws, size_t ws_size,
                              hipStream_t stream) {
  const float* x   = (const float*)d_in[0];
  const float* h   = (const float*)d_in[1];
  const float* c   = (const float*)d_in[2];
  const float* Wxi = (const float*)d_in[3];  const float* bxi = (const float*)d_in[4];
  const float* Whi = (const float*)d_in[5];  const float* bhi = (const float*)d_in[6];
  const float* Wxf = (const float*)d_in[7];  const float* bxf = (const float*)d_in[8];
  const float* Whf = (const float*)d_in[9];  const float* bhf = (const float*)d_in[10];
  const float* Wxo = (const float*)d_in[11]; const float* bxo = (const float*)d_in[12];
  const float* Who = (const float*)d_in[13]; const float* bho = (const float*)d_in[14];
  const float* Wxg = (const float*)d_in[15]; const float* bxg = (const float*)d_in[16];
  const float* Whg = (const float*)d_in[17]; const float* bhg = (const float*)d_in[18];
  float* out = (float*)d_out;

  bf16*  Abuf  = (bf16*)d_ws;                          // 32 MB
  bf16*  Wbuf  = Abuf + (size_t)8192 * 2048;           // 16 MB
  float* Bcomb = (float*)(Wbuf + (size_t)4096 * 2048); // 16 KB

  pack_all<<<12288, 256, 0, stream>>>(x, h,
                                      Wxi, Whi, Wxf, Whf, Wxo, Who, Wxg, Whg,
                                      bxi, bhi, bxf, bhf, bxo, bho, bxg, bhg,
                                      Abuf, Wbuf, Bcomb);
  gemm_lstm<<<dim3(32, 64), 256, 0, stream>>>(Abuf, Wbuf, Bcomb, c, out);
}

// Round 2
// 356.022 us; speedup vs baseline: 1.0085x; 1.0085x over previous
//
#include <hip/hip_runtime.h>
#include <hip/hip_bf16.h>
#include <cstdint>

// VanillaLSTMCell: B=8192, I=H=1024.
// z = [x|h] @ [Wx;Wh]^T + b  (M=8192, N=4096, K=2048), LSTM pointwise fused.
//
// ROUND 6: barrier-free fragment-direct GEMM (round 5) +
//   (a) bijective XCD-aware block swizzle: XCD x owns mb in [8x,8x+8);
//       inner order tiles 8mb x 8nb so concurrent blocks/XCD touch ~4MB A
//       + ~4MB B (~L2-resident) instead of streaming all of B2 per XCD.
//   (b) __launch_bounds__(256,3): cap unified VGPR+AGPR at 170 -> 3 waves/SIMD
//       (was 2) for latency hiding.
//   (c) s_setprio(1) around MFMA clusters (T5; waves here are barrier-free so
//       role diversity exists, unlike the lockstep-null case).

typedef __bf16 bf16;
typedef __attribute__((ext_vector_type(8))) bf16 bf16x8;
typedef __attribute__((ext_vector_type(4))) float f32x4;

#define CN_OFF 8388608  // 8192*1024, c_next offset in d_out

// ---- pack kernel (unchanged from round 5) ----
// blocks [0,8192):    A2[mb(64)][kt(64)][wm(2)][mi(4)][lane(64)][8]
//                     m = mb*128 + wm*64 + mi*16 + (lane&15), k = kt*32 + (lane>>4)*8
// blocks [8192,12288): B2[nb(32)][kt(64)][wn(2)][gate(4)][lane(64)][8]
//                     j = (nb*2+wn)*16 + (lane&15), k = kt*32 + (lane>>4)*8
// Bias: Bcomb[(nb*2+wn)*64 + gate*16 + jl] = bx[j]+bh[j]
__global__ __launch_bounds__(256) void pack_all(
    const float* __restrict__ x, const float* __restrict__ h,
    const float* __restrict__ wxi, const float* __restrict__ whi,
    const float* __restrict__ wxf, const float* __restrict__ whf,
    const float* __restrict__ wxo, const float* __restrict__ who,
    const float* __restrict__ wxg, const float* __restrict__ whg,
    const float* __restrict__ bxi, const float* __restrict__ bhi,
    const float* __restrict__ bxf, const float* __restrict__ bhf,
    const float* __restrict__ bxo, const float* __restrict__ bho,
    const float* __restrict__ bxg, const float* __restrict__ bhg,
    bf16* __restrict__ A2, bf16* __restrict__ B2, float* __restrict__ Bcomb) {
  int b = blockIdx.x;
  if (b < 8192) {
    int chunk = b * 256 + threadIdx.x;        // 2,097,152 chunks of 8
    int lane = chunk & 63;
    int mi   = (chunk >> 6) & 3;
    int wm   = (chunk >> 8) & 1;
    int kt   = (chunk >> 9) & 63;
    int mb   = chunk >> 15;
    int m = mb * 128 + wm * 64 + mi * 16 + (lane & 15);
    int k = kt * 32 + (lane >> 4) * 8;
    const float* src = (k < 1024) ? (x + (size_t)m * 1024 + k)
                                  : (h + (size_t)m * 1024 + (k - 1024));
    f32x4 v0 = *(const f32x4*)src;
    f32x4 v1 = *(const f32x4*)(src + 4);
    bf16x8 o;
    o[0]=(bf16)v0[0]; o[1]=(bf16)v0[1]; o[2]=(bf16)v0[2]; o[3]=(bf16)v0[3];
    o[4]=(bf16)v1[0]; o[5]=(bf16)v1[1]; o[6]=(bf16)v1[2]; o[7]=(bf16)v1[3];
    *(bf16x8*)(A2 + (size_t)chunk * 8) = o;
  } else {
    int chunk = (b - 8192) * 256 + threadIdx.x;  // 1,048,576 chunks of 8
    int lane = chunk & 63;
    int gate = (chunk >> 6) & 3;
    int wn   = (chunk >> 8) & 1;
    int kt   = (chunk >> 9) & 63;
    int nb   = chunk >> 15;
    int jl = lane & 15;
    int j  = (nb * 2 + wn) * 16 + jl;
    int k  = kt * 32 + (lane >> 4) * 8;
    const float* wx = (gate == 0) ? wxi : (gate == 1) ? wxf : (gate == 2) ? wxo : wxg;
    const float* wh = (gate == 0) ? whi : (gate == 1) ? whf : (gate == 2) ? who : whg;
    const float* src = (k < 1024) ? (wx + (size_t)j * 1024 + k)
                                  : (wh + (size_t)j * 1024 + (k - 1024));
    f32x4 v0 = *(const f32x4*)src;
    f32x4 v1 = *(const f32x4*)(src + 4);
    bf16x8 o;
    o[0]=(bf16)v0[0]; o[1]=(bf16)v0[1]; o[2]=(bf16)v0[2]; o[3]=(bf16)v0[3];
    o[4]=(bf16)v1[0]; o[5]=(bf16)v1[1]; o[6]=(bf16)v1[2]; o[7]=(bf16)v1[3];
    *(bf16x8*)(B2 + (size_t)chunk * 8) = o;
    if (kt == 0 && (lane >> 4) == 0) {
      const float* bx = (gate == 0) ? bxi : (gate == 1) ? bxf : (gate == 2) ? bxo : bxg;
      const float* bh = (gate == 0) ? bhi : (gate == 1) ? bhf : (gate == 2) ? bho : bhg;
      Bcomb[(nb * 2 + wn) * 64 + gate * 16 + jl] = bx[j] + bh[j];
    }
  }
}

__device__ __forceinline__ float sigf(float v) { return 1.f / (1.f + __expf(-v)); }
__device__ __forceinline__ float tanhfast(float v) {
  v = fminf(15.f, fmaxf(-15.f, v));
  float e = __expf(2.f * v);
  return (e - 1.f) / (e + 1.f);
}

// ---- barrier-free fragment-direct GEMM + register-resident LSTM epilogue ----
__global__ __launch_bounds__(256, 3) void gemm_lstm(const bf16* __restrict__ A2,
                                                    const bf16* __restrict__ B2,
                                                    const float* __restrict__ Bcomb,
                                                    const float* __restrict__ c,
                                                    float* __restrict__ out) {
  const int t    = threadIdx.x;
  const int wave = t >> 6;
  const int lane = t & 63;

  // ---- bijective XCD-aware swizzle (8 XCDs, 2048 blocks, round-robin bid%8) ----
  // xcd = bid&7 owns mb in [xcd*8, xcd*8+8); inner order tiles 8mb x 8nb so the
  // ~96 concurrent blocks per XCD touch ~4MB of A2 + ~4MB of B2 (L2-sized).
  const int bid = blockIdx.x;
  const int xcd = bid & 7;
  const int idx = bid >> 3;           // 0..255
  const int nbChunk = idx >> 6;       // 0..3  (8 nb each)
  const int inner   = idx & 63;
  const int mbLocal = inner >> 3;     // 0..7
  const int nbi     = inner & 7;      // 0..7
  const int mb = xcd * 8 + mbLocal;   // 0..63
  const int nb = nbChunk * 8 + nbi;   // 0..31

  const int wm = wave >> 1;      // wave's 64-row half
  const int wn = wave & 1;       // wave's 64-col half
  const int lrow = lane & 15;
  const int lkg  = lane >> 4;

  // fragment-major bases: offset(kt,frag) = kt*4096 + frag*512 (elements)
  const bf16* pa = A2 + (size_t)mb * 262144 + wm * 2048 + lane * 8;
  const bf16* pb = B2 + (size_t)nb * 262144 + wn * 2048 + lane * 8;

  f32x4 acc[4][4] = {};   // acc[mi][gate]
  bf16x8 a0[4], b0[4], a1[4], b1[4];

#pragma unroll
  for (int i = 0; i < 4; ++i) {
    a0[i] = *(const bf16x8*)(pa + i * 512);
    b0[i] = *(const bf16x8*)(pb + i * 512);
  }
#pragma unroll
  for (int i = 0; i < 4; ++i) {
    a1[i] = *(const bf16x8*)(pa + 4096 + i * 512);
    b1[i] = *(const bf16x8*)(pb + 4096 + i * 512);
  }

  for (int kt = 0; kt < 64; kt += 2) {
    __builtin_amdgcn_s_setprio(1);
#pragma unroll
    for (int mi = 0; mi < 4; ++mi)
#pragma unroll
      for (int ni = 0; ni < 4; ++ni)
        acc[mi][ni] = __builtin_amdgcn_mfma_f32_16x16x32_bf16(a0[mi], b0[ni], acc[mi][ni], 0, 0, 0);
    __builtin_amdgcn_s_setprio(0);
    if (kt + 2 < 64) {
      const bf16* qa = pa + (size_t)(kt + 2) * 4096;
      const bf16* qb = pb + (size_t)(kt + 2) * 4096;
#pragma unroll
      for (int i = 0; i < 4; ++i) {
        a0[i] = *(const bf16x8*)(qa + i * 512);
        b0[i] = *(const bf16x8*)(qb + i * 512);
      }
    }
    __builtin_amdgcn_s_setprio(1);
#pragma unroll
    for (int mi = 0; mi < 4; ++mi)
#pragma unroll
      for (int ni = 0; ni < 4; ++ni)
        acc[mi][ni] = __builtin_amdgcn_mfma_f32_16x16x32_bf16(a1[mi], b1[ni], acc[mi][ni], 0, 0, 0);
    __builtin_amdgcn_s_setprio(0);
    if (kt + 3 < 64) {
      const bf16* qa = pa + (size_t)(kt + 3) * 4096;
      const bf16* qb = pb + (size_t)(kt + 3) * 4096;
#pragma unroll
      for (int i = 0; i < 4; ++i) {
        a1[i] = *(const bf16x8*)(qa + i * 512);
        b1[i] = *(const bf16x8*)(qb + i * 512);
      }
    }
  }

  // ---- register-resident LSTM epilogue (round-4 mapping) ----
  // Lane (lrow,lkg): j = (nb*2+wn)*16 + lrow; rows = mb*128 + wm*64 + mi*16 + lkg*4 + r
  const int jg = (nb * 2 + wn) * 16 + lrow;
  const int bbase = (nb * 2 + wn) * 64 + lrow;
  const float bi  = Bcomb[bbase +  0];
  const float bf_ = Bcomb[bbase + 16];
  const float bo  = Bcomb[bbase + 32];
  const float bg  = Bcomb[bbase + 48];

#pragma unroll
  for (int mi = 0; mi < 4; ++mi) {
    const int row0 = mb * 128 + wm * 64 + mi * 16 + lkg * 4;
    float cv[4];
#pragma unroll
    for (int r = 0; r < 4; ++r)
      cv[r] = c[(size_t)(row0 + r) * 1024 + jg];
#pragma unroll
    for (int r = 0; r < 4; ++r) {
      float zi = acc[mi][0][r] + bi;
      float zf = acc[mi][1][r] + bf_;
      float zo = acc[mi][2][r] + bo;
      float zg = acc[mi][3][r] + bg;
      float it = sigf(zi), ft = sigf(zf), ot = sigf(zo), gt = tanhfast(zg);
      float cn = ft * cv[r] + it * gt;
      size_t off = (size_t)(row0 + r) * 1024 + jg;
      out[off] = ot * tanhfast(cn);        // h_next
      out[CN_OFF + off] = cn;              // c_next
    }
  }
}

extern "C" void kernel_launch(void* const* d_in, const int* in_sizes, int n_in,
                              void* d_out, int out_size, void* d_ws, size_t ws_size,
                              hipStream_t stream) {
  const float* x   = (const float*)d_in[0];
  const float* h   = (const float*)d_in[1];
  const float* c   = (const float*)d_in[2];
  const float* Wxi = (const float*)d_in[3];  const float* bxi = (const float*)d_in[4];
  const float* Whi = (const float*)d_in[5];  const float* bhi = (const float*)d_in[6];
  const float* Wxf = (const float*)d_in[7];  const float* bxf = (const float*)d_in[8];
  const float* Whf = (const float*)d_in[9];  const float* bhf = (const float*)d_in[10];
  const float* Wxo = (const float*)d_in[11]; const float* bxo = (const float*)d_in[12];
  const float* Who = (const float*)d_in[13]; const float* bho = (const float*)d_in[14];
  const float* Wxg = (const float*)d_in[15]; const float* bxg = (const float*)d_in[16];
  const float* Whg = (const float*)d_in[17]; const float* bhg = (const float*)d_in[18];
  float* out = (float*)d_out;

  bf16*  Abuf  = (bf16*)d_ws;                          // 32 MB
  bf16*  Wbuf  = Abuf + (size_t)8192 * 2048;           // 16 MB
  float* Bcomb = (float*)(Wbuf + (size_t)4096 * 2048); // 16 KB

  pack_all<<<12288, 256, 0, stream>>>(x, h,
                                      Wxi, Whi, Wxf, Whf, Wxo, Who, Wxg, Whg,
                                      bxi, bhi, bxf, bhf, bxo, bho, bxg, bhg,
                                      Abuf, Wbuf, Bcomb);
  gemm_lstm<<<2048, 256, 0, stream>>>(Abuf, Wbuf, Bcomb, c, out);
}

// Round 3
// 316.872 us; speedup vs baseline: 1.1331x; 1.1236x over previous
//
#include <hip/hip_runtime.h>
#include <hip/hip_bf16.h>
#include <cstdint>

// VanillaLSTMCell: B=8192, I=H=1024.
// z = [x|h] @ [Wx;Wh]^T + b  (M=8192, N=4096, K=2048), LSTM pointwise fused.
//
// ROUND 7:
//  gemm: 256x256 LDS-shared tile (8 waves, BK=64, double-buffered 128KB LDS).
//    A2/B2 are fragment-major -> global_load_lds stages 16KB-contiguous chunks
//    with LINEAR LDS dest; all ds_reads are contiguous b128 (conflict-free, no
//    swizzle needed). One vmcnt(0)+barrier per K-tile (T3 minimum skeleton),
//    stage issued FIRST so loads fly under ~700cy of compute. Intensity 32 ->
//    128 FLOP/B (kills the L2-BW wall diagnosed in round 2).
//  pack: rewritten as coalesced row-reads -> LDS transpose (XOR 16B-chunk
//    swizzle, G4) -> coalesced fragment-major writes. Old pack read 16-row
//    x 128B column tiles (4KB stride) and ran at ~0.85 TB/s.

typedef __bf16 bf16;
typedef __attribute__((ext_vector_type(8))) bf16 bf16x8;
typedef __attribute__((ext_vector_type(4))) float f32x4;

#define CN_OFF 8388608  // 8192*1024, c_next offset in d_out

__device__ __forceinline__ void gload16(const bf16* g, bf16* l) {
  __builtin_amdgcn_global_load_lds(
      (const __attribute__((address_space(1))) void*)g,
      (__attribute__((address_space(3))) void*)l, 16, 0, 0);
}

__device__ __forceinline__ bf16x8 cvt8(f32x4 v0, f32x4 v1) {
  bf16x8 o;
  o[0]=(bf16)v0[0]; o[1]=(bf16)v0[1]; o[2]=(bf16)v0[2]; o[3]=(bf16)v0[3];
  o[4]=(bf16)v1[0]; o[5]=(bf16)v1[1]; o[6]=(bf16)v1[2]; o[7]=(bf16)v1[3];
  return o;
}

// ---- pack: coalesced read -> LDS transpose -> coalesced fragment write ----
// A2[mb(64)][kt(64)][wm(2)][mi(4)][lane(64)][8]:
//   m = mb*128 + wm*64 + mi*16 + (lane&15), k = kt*32 + (lane>>4)*8
// B2[nb(32)][kt(64)][wn(2)][gate(4)][lane(64)][8]:
//   j = (nb*2+wn)*16 + (lane&15), k = kt*32 + (lane>>4)*8
// A-side blocks [0,2048): bid = mb<<5 | wm<<4 | q ; tile = 64 rows x 128 k
// B-side blocks [2048,4096): bid2 = nb<<6 | gate<<4 | q ; tile = 32 j x 128 k
__global__ __launch_bounds__(256) void pack_all(
    const float* __restrict__ x, const float* __restrict__ h,
    const float* __restrict__ wxi, const float* __restrict__ whi,
    const float* __restrict__ wxf, const float* __restrict__ whf,
    const float* __restrict__ wxo, const float* __restrict__ who,
    const float* __restrict__ wxg, const float* __restrict__ whg,
    const float* __restrict__ bxi, const float* __restrict__ bhi,
    const float* __restrict__ bxf, const float* __restrict__ bhf,
    const float* __restrict__ bxo, const float* __restrict__ bho,
    const float* __restrict__ bxg, const float* __restrict__ bhg,
    bf16* __restrict__ A2, bf16* __restrict__ B2, float* __restrict__ Bcomb) {
  __shared__ __align__(16) bf16 lds[8192];   // 16KB: [row][128] with XOR swizzle
  const int t = threadIdx.x;
  const int bid = blockIdx.x;

  if (bid < 2048) {
    // ---- A side ----
    const int mb = bid >> 5;
    const int wm = (bid >> 4) & 1;
    const int q  = bid & 15;                 // kt-quad: cols [q*128, q*128+128)
    const int rowbase = mb * 128 + wm * 64;
    const float* srcM; int k0;
    if (q < 8) { srcM = x; k0 = q * 128; } else { srcM = h; k0 = q * 128 - 1024; }
#pragma unroll
    for (int r = 0; r < 4; ++r) {
      const int rl = r * 16 + (t >> 4);      // 0..63
      const int cc = (t & 15) * 8;           // 0..120
      const float* s = srcM + (size_t)(rowbase + rl) * 1024 + k0 + cc;
      f32x4 v0 = *(const f32x4*)s;
      f32x4 v1 = *(const f32x4*)(s + 4);
      const int chunkS = (t & 15) ^ (rl & 7);
      *(bf16x8*)((char*)lds + rl * 256 + chunkS * 16) = cvt8(v0, v1);
    }
    __syncthreads();
#pragma unroll
    for (int r = 0; r < 4; ++r) {
      const int idx = r * 256 + t;           // 0..1023
      const int fj  = idx >> 6;              // 0..15 = ktL*4 + mi
      const int ktL = fj >> 2, mi = fj & 3;
      const int l   = idx & 63;
      const int srow = mi * 16 + (l & 15);
      const int chunkS = (ktL * 4 + (l >> 4)) ^ (srow & 7);
      bf16x8 o = *(const bf16x8*)((const char*)lds + srow * 256 + chunkS * 16);
      size_t el = ((size_t)mb * 64 + q * 4 + ktL) * 4096 + (size_t)wm * 2048 + mi * 512 + l * 8;
      *(bf16x8*)(A2 + el) = o;
    }
  } else {
    // ---- B (weights) side ----
    const int bid2 = bid - 2048;
    const int nb   = bid2 >> 6;
    const int gate = (bid2 >> 4) & 3;
    const int q    = bid2 & 15;
    const float* wxm = (gate == 0) ? wxi : (gate == 1) ? wxf : (gate == 2) ? wxo : wxg;
    const float* whm = (gate == 0) ? whi : (gate == 1) ? whf : (gate == 2) ? who : whg;
    const float* srcM; int k0;
    if (q < 8) { srcM = wxm; k0 = q * 128; } else { srcM = whm; k0 = q * 128 - 1024; }
    const int jbase = nb * 32;
#pragma unroll
    for (int r = 0; r < 2; ++r) {
      const int rl = r * 16 + (t >> 4);      // 0..31
      const int cc = (t & 15) * 8;
      const float* s = srcM + (size_t)(jbase + rl) * 1024 + k0 + cc;
      f32x4 v0 = *(const f32x4*)s;
      f32x4 v1 = *(const f32x4*)(s + 4);
      const int chunkS = (t & 15) ^ (rl & 7);
      *(bf16x8*)((char*)lds + rl * 256 + chunkS * 16) = cvt8(v0, v1);
    }
    __syncthreads();
#pragma unroll
    for (int r = 0; r < 2; ++r) {
      const int idx = r * 256 + t;           // 0..511
      const int fj  = idx >> 6;              // 0..7 = ktL*2 + wn
      const int ktL = fj >> 1, wn = fj & 1;
      const int l   = idx & 63;
      const int srow = wn * 16 + (l & 15);
      const int chunkS = (ktL * 4 + (l >> 4)) ^ (srow & 7);
      bf16x8 o = *(const bf16x8*)((const char*)lds + srow * 256 + chunkS * 16);
      size_t el = ((size_t)nb * 64 + q * 4 + ktL) * 4096 + (size_t)wn * 2048 + gate * 512 + l * 8;
      *(bf16x8*)(B2 + el) = o;
    }
    if (q == 0 && t < 32) {
      const float* bxv = (gate == 0) ? bxi : (gate == 1) ? bxf : (gate == 2) ? bxo : bxg;
      const float* bhv = (gate == 0) ? bhi : (gate == 1) ? bhf : (gate == 2) ? bho : bhg;
      const int wn = t >> 4, jl = t & 15;
      const int j = nb * 32 + wn * 16 + jl;
      Bcomb[(nb * 2 + wn) * 64 + gate * 16 + jl] = bxv[j] + bhv[j];
    }
  }
}

__device__ __forceinline__ float sigf(float v) { return 1.f / (1.f + __expf(-v)); }
__device__ __forceinline__ float tanhfast(float v) {
  v = fminf(15.f, fmaxf(-15.f, v));
  float e = __expf(2.f * v);
  return (e - 1.f) / (e + 1.f);
}

// ---- 256x256 LDS-shared GEMM (8 waves) + register-resident LSTM epilogue ----
// Block: rows [bm*256, +256) (2 mb units), z-cols [bn*256, +256) (2 nb units).
// Wave (wr,wc): wr in {0,1} -> mbL; wc in {0..3} -> (nbL = wc>>1, wn = wc&1).
// Per K-tile (BK=64 = 2 kt units): stage 64KB (4 regions x 16KB contiguous)
// into buf[p^1] via global_load_lds; compute from buf[p]; one barrier/tile.
__global__ __launch_bounds__(512, 2) void gemm_lstm(const bf16* __restrict__ A2,
                                                    const bf16* __restrict__ B2,
                                                    const float* __restrict__ Bcomb,
                                                    const float* __restrict__ c,
                                                    float* __restrict__ out) {
  __shared__ __align__(16) bf16 lds[65536];   // 128KB = 2 buf x 32768 elems
  const int t    = threadIdx.x;
  const int wave = t >> 6;
  const int lane = t & 63;

  // XCD swizzle: xcd owns bn pair {2x,2x+1} (B2 slice 2MB -> L2-resident).
  const int bid = blockIdx.x;          // 512 blocks
  const int xcd = bid & 7;
  const int idx = bid >> 3;            // 0..63
  const int bn  = xcd * 2 + (idx & 1); // 0..15
  const int bm  = idx >> 1;            // 0..31

  const int wr  = wave >> 2;           // 0..1: mbL
  const int wc  = wave & 3;            // 0..3
  const int nbL = wc >> 1, wn = wc & 1;
  const int lrow = lane & 15, lkg = lane >> 4;

  const int tEl = t * 8;               // per-thread element offset in a 4096-elem half
  const int wEl = (t & ~63) * 8;       // wave-uniform LDS base element

  const bf16* aSrc0 = A2 + (size_t)(2 * bm)     * 64 * 4096;
  const bf16* aSrc1 = A2 + (size_t)(2 * bm + 1) * 64 * 4096;
  const bf16* bSrc0 = B2 + (size_t)(2 * bn)     * 64 * 4096;
  const bf16* bSrc1 = B2 + (size_t)(2 * bn + 1) * 64 * 4096;

  auto stage = [&](int tile, int buf) {
    const size_t kOff = (size_t)tile * 8192;   // 2 kt * 4096 elems
    bf16* d = lds + buf * 32768;
    const bf16* s0 = aSrc0 + kOff;
    const bf16* s1 = aSrc1 + kOff;
    const bf16* s2 = bSrc0 + kOff;
    const bf16* s3 = bSrc1 + kOff;
#pragma unroll
    for (int hh = 0; hh < 2; ++hh) {
      gload16(s0 + hh * 4096 + tEl, d +         hh * 4096 + wEl);
      gload16(s1 + hh * 4096 + tEl, d +  8192 + hh * 4096 + wEl);
      gload16(s2 + hh * 4096 + tEl, d + 16384 + hh * 4096 + wEl);
      gload16(s3 + hh * 4096 + tEl, d + 24576 + hh * 4096 + wEl);
    }
  };

  f32x4 acc[8][4] = {};   // acc[amI][gate]

  stage(0, 0);
  __syncthreads();        // implicit vmcnt(0): buf0 ready

  for (int kt2 = 0; kt2 < 32; ++kt2) {
    const int p = kt2 & 1;
    if (kt2 + 1 < 32) stage(kt2 + 1, p ^ 1);   // issue EARLY, in flight under compute
    const bf16* bufA = lds + p * 32768 + wr * 8192;
    const bf16* bufB = lds + p * 32768 + 16384 + nbL * 8192 + wn * 2048;
#pragma unroll
    for (int ktL = 0; ktL < 2; ++ktL) {
      bf16x8 af[8], bfr[4];
#pragma unroll
      for (int i = 0; i < 8; ++i)
        af[i] = *(const bf16x8*)(bufA + ktL * 4096 + i * 512 + lane * 8);
#pragma unroll
      for (int g = 0; g < 4; ++g)
        bfr[g] = *(const bf16x8*)(bufB + ktL * 4096 + g * 512 + lane * 8);
      __builtin_amdgcn_s_setprio(1);
#pragma unroll
      for (int i = 0; i < 8; ++i)
#pragma unroll
        for (int g = 0; g < 4; ++g)
          acc[i][g] = __builtin_amdgcn_mfma_f32_16x16x32_bf16(af[i], bfr[g], acc[i][g], 0, 0, 0);
      __builtin_amdgcn_s_setprio(0);
    }
    __syncthreads();      // implicit vmcnt(0)+lgkmcnt(0): next buf staged, this buf free
  }

  // ---- register-resident LSTM epilogue ----
  const int nb = bn * 2 + nbL;
  const int jg = (nb * 2 + wn) * 16 + lrow;
  const int bbase = (nb * 2 + wn) * 64 + lrow;
  const float bi  = Bcomb[bbase +  0];
  const float bf_ = Bcomb[bbase + 16];
  const float bo  = Bcomb[bbase + 32];
  const float bg  = Bcomb[bbase + 48];

#pragma unroll
  for (int i = 0; i < 8; ++i) {
    const int row0 = (2 * bm + wr) * 128 + (i >> 2) * 64 + (i & 3) * 16 + lkg * 4;
    float cv[4];
#pragma unroll
    for (int r = 0; r < 4; ++r)
      cv[r] = c[(size_t)(row0 + r) * 1024 + jg];
#pragma unroll
    for (int r = 0; r < 4; ++r) {
      float zi = acc[i][0][r] + bi;
      float zf = acc[i][1][r] + bf_;
      float zo = acc[i][2][r] + bo;
      float zg = acc[i][3][r] + bg;
      float it = sigf(zi), ft = sigf(zf), ot = sigf(zo), gt = tanhfast(zg);
      float cn = ft * cv[r] + it * gt;
      size_t off = (size_t)(row0 + r) * 1024 + jg;
      out[off] = ot * tanhfast(cn);        // h_next
      out[CN_OFF + off] = cn;              // c_next
    }
  }
}

extern "C" void kernel_launch(void* const* d_in, const int* in_sizes, int n_in,
                              void* d_out, int out_size, void* d_ws, size_t ws_size,
                              hipStream_t stream) {
  const float* x   = (const float*)d_in[0];
  const float* h   = (const float*)d_in[1];
  const float* c   = (const float*)d_in[2];
  const float* Wxi = (const float*)d_in[3];  const float* bxi = (const float*)d_in[4];
  const float* Whi = (const float*)d_in[5];  const float* bhi = (const float*)d_in[6];
  const float* Wxf = (const float*)d_in[7];  const float* bxf = (const float*)d_in[8];
  const float* Whf = (const float*)d_in[9];  const float* bhf = (const float*)d_in[10];
  const float* Wxo = (const float*)d_in[11]; const float* bxo = (const float*)d_in[12];
  const float* Who = (const float*)d_in[13]; const float* bho = (const float*)d_in[14];
  const float* Wxg = (const float*)d_in[15]; const float* bxg = (const float*)d_in[16];
  const float* Whg = (const float*)d_in[17]; const float* bhg = (const float*)d_in[18];
  float* out = (float*)d_out;

  bf16*  Abuf  = (bf16*)d_ws;                          // 32 MB
  bf16*  Wbuf  = Abuf + (size_t)8192 * 2048;           // 16 MB
  float* Bcomb = (float*)(Wbuf + (size_t)4096 * 2048); // 16 KB

  pack_all<<<4096, 256, 0, stream>>>(x, h,
                                     Wxi, Whi, Wxf, Whf, Wxo, Who, Wxg, Whg,
                                     bxi, bhi, bxf, bhf, bxo, bho, bxg, bhg,
                                     Abuf, Wbuf, Bcomb);
  gemm_lstm<<<512, 512, 0, stream>>>(Abuf, Wbuf, Bcomb, c, out);
}